// Round 6
// baseline (33.156 us; speedup 1.0000x reference)
//
#include <hip/hip_runtime.h>

#define H 128
#define N 1024
#define SLOTS 136      // fixed: P8 + negatives + tail pad == 17 groups of 8
#define SLOTS_A 144    // allocated rows (+8 prefetch over-read slack)

// ---------------------------------------------------------------------------
// prep: grid N/4 = 256 blocks x 512 threads.
//   Sign-partition permutation of h (W2>=0 first). Slots layout (fixed 136):
//     [0,P) positives, [P,P8) zero pad, [P8,P8+H-P) negatives,
//     [P8+H-P,136) zero pad.   P8 = ceil8(P).
//   Identity: sum_h w2*relu(L+b1+R) = 0.5*(rowconst + c_j) + sum_slots s*|u|,
//     u = w2*(L+b1+R), s = +-0.5 uniform within each 8-group; rowconst
//     cancels in softmax. Pad slots have u=0 -> contribute 0 either sign.
//   Outputs: LpS[slot][i] = w2*(L+b1), Rt[slot][j] = w2*R (both slot-major,
//   staged in LDS, one float4 store per slot), c[j], meta[0] = P8.
// ---------------------------------------------------------------------------
__global__ __launch_bounds__(512) void prep_kernel(
    const float* __restrict__ x, const float* __restrict__ W1,
    const float* __restrict__ b1, const float* __restrict__ W2,
    float* __restrict__ LpS, float* __restrict__ Rt,
    float* __restrict__ c, int* __restrict__ meta)
{
    constexpr int PF = 16;
    __shared__ float e_s[4][H];
    __shared__ float cred[4][2];
    __shared__ int   slot_s[H];
    __shared__ int   cnt_s[2];
    __shared__ int   meta_s[2];            // P8, P
    __shared__ float4 stageL[SLOTS];
    __shared__ float4 stageR[SLOTS];
    const int t = threadIdx.x;
    const int i0 = blockIdx.x * 4;

    // ---- sign ballots (waves 0,1 cover h = t) ----
    bool pos = false; int rank = 0;
    if (t < H) {
        const int lane = t & 63;
        pos = (W2[t] >= 0.f);
        const unsigned long long bal = __ballot(pos);
        rank = __popcll(bal & ((1ull << lane) - 1ull));
        if (lane == 0) cnt_s[t >> 6] = __popcll(bal);
    }
    // ---- normalize rows (waves 0-3, wave w owns row w) ----
    if (t < 256) {
        const int row = t >> 6, lane = t & 63;
        const float2 v = *reinterpret_cast<const float2*>(&x[(i0 + row) * H + 2 * lane]);
        float s = v.x * v.x + v.y * v.y;
#pragma unroll
        for (int off = 32; off; off >>= 1) s += __shfl_xor(s, off);
        const float rn = 1.0f / fmaxf(sqrtf(s), 1e-12f);
        e_s[row][2 * lane]     = v.x * rn;
        e_s[row][2 * lane + 1] = v.y * rn;
    }
    __syncthreads();

    // ---- permutation slots ----
    if (t < H) {
        const int c0 = cnt_s[0];
        const int P  = c0 + cnt_s[1];
        const int P8 = (P + 7) & ~7;
        const int lane = t & 63;
        int slot;
        if (pos) slot = (t < 64 ? 0 : c0) + rank;
        else     slot = P8 + (t < 64 ? 0 : 64 - c0) + (lane - rank);
        slot_s[t] = slot;
        if (t == 0) { meta_s[0] = P8; meta_s[1] = P; }
    }
    __syncthreads();

    // ---- dual GEMV, PF=16 register-pipelined W1 column loads ----
    const int h = t & (H - 1);
    const int q = t >> 7;                  // 0,1 -> L ; 2,3 -> R
    const int r0 = (q & 1) * 2;            // row pair {0,1} or {2,3}
    const float* Wb = W1 + (q >= 2 ? H * H : 0) + h;

    float acc0 = 0.f, acc1 = 0.f;
    float wbuf[PF];
#pragma unroll
    for (int p = 0; p < PF; ++p) wbuf[p] = Wb[p * H];

    for (int kb = 0; kb < H - PF; kb += PF) {
#pragma unroll
        for (int p = 0; p < PF; ++p) {
            const float w = wbuf[p];
            wbuf[p] = Wb[(kb + p + PF) * H];
            acc0 = fmaf(e_s[r0][kb + p],     w, acc0);
            acc1 = fmaf(e_s[r0 + 1][kb + p], w, acc1);
        }
    }
#pragma unroll
    for (int p = 0; p < PF; ++p) {
        const int k = H - PF + p;
        acc0 = fmaf(e_s[r0][k],     wbuf[p], acc0);
        acc1 = fmaf(e_s[r0 + 1][k], wbuf[p], acc1);
    }

    const float w2h = W2[h];
    const int slot = slot_s[h];
    float* stg = q < 2 ? (float*)&stageL[slot] : (float*)&stageR[slot];
    if (q < 2) {
        const float bb = b1[h];
        stg[r0]     = w2h * (acc0 + bb);
        stg[r0 + 1] = w2h * (acc1 + bb);
    } else {
        const float v0 = w2h * acc0, v1 = w2h * acc1;
        stg[r0]     = v0;
        stg[r0 + 1] = v1;
        float s0 = v0, s1 = v1;            // c_j partials over h
#pragma unroll
        for (int off = 32; off; off >>= 1) {
            s0 += __shfl_xor(s0, off);
            s1 += __shfl_xor(s1, off);
        }
        const int wv = t >> 6;             // 4..7
        if ((t & 63) == 0) { cred[wv - 4][0] = s0; cred[wv - 4][1] = s1; }
    }
    // zero the pad slots in the stage
    {
        const int P8m = meta_s[0], Pm = meta_s[1];
        const float4 z = {0.f, 0.f, 0.f, 0.f};
        if (t >= 64 && t < 72) {                       // [P, P8)
            const int k = t - 64;
            if (k < P8m - Pm) { stageL[Pm + k] = z; stageR[Pm + k] = z; }
        } else if (t >= 72 && t < 80) {                // [P8+H-P, 136)
            const int k = t - 72;
            const int base2 = P8m + (H - Pm);
            if (k < SLOTS - base2) { stageL[base2 + k] = z; stageR[base2 + k] = z; }
        }
    }
    __syncthreads();

    if (t < 4)
        c[i0 + t] = cred[(t >> 1) * 2][t & 1] + cred[(t >> 1) * 2 + 1][t & 1];
    if (t < SLOTS)
        *reinterpret_cast<float4*>(&LpS[t * N + i0]) = stageL[t];
    else if (t >= 256 && t < 256 + SLOTS)
        *reinterpret_cast<float4*>(&Rt[(t - 256) * N + i0]) = stageR[t - 256];
    if (blockIdx.x == 0 && t == 0) meta[0] = meta_s[0];
}

// ---------------------------------------------------------------------------
// adj: grid N/4 = 256 blocks x 256 threads (1 wave/SIMD, ILP-covered).
//   thread t: rows i0..i0+3 (TI=4), cols j0=4t..4t+3 (TJ=4).
//   Fixed 17 groups of 8 slots; group sign sg = (8g<P8) ? +0.5 : -0.5
//   (wave-uniform select, once per group). Per h per thread:
//   1 ds_read_b128 (L bcast) + 1 global dwordx4 (R coalesced) + 32 VALU
//   (add + fma-with-|.| per element). R prefetched one full group (8) ahead.
//   logit[i][j] = 0.5*c_j + sum sg*|lv+r|; block-local softmax over j.
// ---------------------------------------------------------------------------
__global__ __launch_bounds__(256) void adj_kernel(
    const float* __restrict__ LpS, const float* __restrict__ Rt,
    const float* __restrict__ c, const int* __restrict__ meta,
    float* __restrict__ out)
{
    constexpr int II = 4, JJ = 4;
    __shared__ float4 LsT[SLOTS];
    __shared__ float red_m[II][4];
    __shared__ float red_s[II][4];

    const int t = threadIdx.x;
    const int lane = t & 63, wave = t >> 6;
    const int i0 = blockIdx.x * II;
    const int j0 = t * JJ;

    const int P8 = meta[0];

    if (t < SLOTS)
        LsT[t] = *reinterpret_cast<const float4*>(&LpS[t * N + i0]);
    const float4 cj = *reinterpret_cast<const float4*>(&c[j0]);
    __syncthreads();

    float acc[II][JJ];
    const float* cjp = &cj.x;
#pragma unroll
    for (int ii = 0; ii < II; ++ii)
#pragma unroll
        for (int jj = 0; jj < JJ; ++jj) acc[ii][jj] = 0.5f * cjp[jj];

    const float* Rp = Rt + j0;
    float4 rbuf[8];
#pragma unroll
    for (int p = 0; p < 8; ++p)
        rbuf[p] = *reinterpret_cast<const float4*>(&Rp[p * N]);

#pragma unroll 1
    for (int g = 0; g < SLOTS / 8; ++g) {
        const float sg = (8 * g < P8) ? 0.5f : -0.5f;
#pragma unroll
        for (int p = 0; p < 8; ++p) {
            const int s = 8 * g + p;
            const float4 r = rbuf[p];
            rbuf[p] = *reinterpret_cast<const float4*>(&Rp[(s + 8) * N]);
            const float4 lv = LsT[s];
            const float* lp = &lv.x;
            const float* rp = &r.x;
#pragma unroll
            for (int ii = 0; ii < II; ++ii)
#pragma unroll
                for (int jj = 0; jj < JJ; ++jj)
                    acc[ii][jj] = fmaf(sg, fabsf(lp[ii] + rp[jj]), acc[ii][jj]);
        }
    }

    // ---- softmax over j (block = full 1024-col row) ----
#pragma unroll
    for (int ii = 0; ii < II; ++ii) {
        float m = fmaxf(fmaxf(acc[ii][0], acc[ii][1]),
                        fmaxf(acc[ii][2], acc[ii][3]));
#pragma unroll
        for (int off = 32; off; off >>= 1) m = fmaxf(m, __shfl_xor(m, off));
        if (lane == 0) red_m[ii][wave] = m;
    }
    __syncthreads();

    float mm[II];
#pragma unroll
    for (int ii = 0; ii < II; ++ii)
        mm[ii] = fmaxf(fmaxf(red_m[ii][0], red_m[ii][1]),
                       fmaxf(red_m[ii][2], red_m[ii][3]));

#pragma unroll
    for (int ii = 0; ii < II; ++ii) {
        float s = 0.f;
#pragma unroll
        for (int jj = 0; jj < JJ; ++jj) {
            acc[ii][jj] = expf(acc[ii][jj] - mm[ii]);
            s += acc[ii][jj];
        }
#pragma unroll
        for (int off = 32; off; off >>= 1) s += __shfl_xor(s, off);
        if (lane == 0) red_s[ii][wave] = s;
    }
    __syncthreads();

#pragma unroll
    for (int ii = 0; ii < II; ++ii) {
        const float s = red_s[ii][0] + red_s[ii][1] + red_s[ii][2] + red_s[ii][3];
        const float rcp = 1.0f / s;
        float4 o;
        o.x = acc[ii][0] * rcp; o.y = acc[ii][1] * rcp;
        o.z = acc[ii][2] * rcp; o.w = acc[ii][3] * rcp;
        *reinterpret_cast<float4*>(&out[(i0 + ii) * N + j0]) = o;
    }
}

extern "C" void kernel_launch(void* const* d_in, const int* in_sizes, int n_in,
                              void* d_out, int out_size, void* d_ws, size_t ws_size,
                              hipStream_t stream) {
    const float* x  = (const float*)d_in[0];   // (N,H)
    const float* W1 = (const float*)d_in[1];   // (2H,H)
    const float* b1 = (const float*)d_in[2];   // (H,)
    const float* W2 = (const float*)d_in[3];   // (H,1)
    // d_in[4] = b2 — cancels under softmax, not needed.
    float* out = (float*)d_out;

    float* wsf = (float*)d_ws;
    float* LpS = wsf;                    // SLOTS_A * N
    float* Rt  = LpS + SLOTS_A * N;      // SLOTS_A * N
    float* cc  = Rt + SLOTS_A * N;       // N
    int*   meta = (int*)(cc + N);        // 1 int

    prep_kernel<<<N / 4, 512, 0, stream>>>(x, W1, b1, W2, LpS, Rt, cc, meta);
    adj_kernel<<<N / 4, 256, 0, stream>>>(LpS, Rt, cc, meta, out);
}

// Round 8
// 30.338 us; speedup vs baseline: 1.0929x; 1.0929x over previous
//
#include <hip/hip_runtime.h>

#define H 128
#define N 1024
#define HPAD 136   // +8 rows prefetch over-read slack

// ---------------------------------------------------------------------------
// Identity: relu(v)*w = 0.5*w*v + w*|v/2|,  v = L~ + b1 + R~  (w signed!)
//   logit[i][j] = const_i + 0.5*c_j + sum_h w_h * |A[h,i] + B[h,j]|
//   A = 0.5*(L~+b1), B = 0.5*R~, c_j = sum_h w_h*R~[j,h]; const_i cancels
//   in softmax; b2 cancels too.
//
// prep: grid N/4 = 256 blocks x 512 threads.
//   waves 0-3 normalize rows; q=t>>7: 0,1 -> A-half of W1, 2,3 -> B-half;
//   PF=8 register-pipelined W1 column loads; results staged in LDS as
//   float4[h], then one 16B store per slot:
//     At[h][i0..i0+3], Bt[h][i0..i0+3]  (h-major, i minor)
//   c via shuffle+cred reduction.
// ---------------------------------------------------------------------------
__global__ __launch_bounds__(512) void prep_kernel(
    const float* __restrict__ x, const float* __restrict__ W1,
    const float* __restrict__ b1, const float* __restrict__ W2,
    float* __restrict__ At, float* __restrict__ Bt,
    float* __restrict__ c)
{
    constexpr int PF = 8;
    __shared__ float e_s[4][H];
    __shared__ float cred[4][2];
    __shared__ float4 stageA[H];
    __shared__ float4 stageB[H];
    const int t = threadIdx.x;
    const int i0 = blockIdx.x * 4;

    // ---- normalize rows (waves 0-3, wave w owns row w) ----
    if (t < 256) {
        const int row = t >> 6, lane = t & 63;
        const float2 v = *reinterpret_cast<const float2*>(&x[(i0 + row) * H + 2 * lane]);
        float s = v.x * v.x + v.y * v.y;
#pragma unroll
        for (int off = 32; off; off >>= 1) s += __shfl_xor(s, off);
        const float rn = 1.0f / fmaxf(sqrtf(s), 1e-12f);
        e_s[row][2 * lane]     = v.x * rn;
        e_s[row][2 * lane + 1] = v.y * rn;
    }
    __syncthreads();

    // ---- dual GEMV, PF=8 register-pipelined W1 column loads ----
    const int h = t & (H - 1);
    const int q = t >> 7;                  // 0,1 -> A ; 2,3 -> B
    const int r0 = (q & 1) * 2;            // row pair {0,1} or {2,3}
    const float* Wb = W1 + (q >= 2 ? H * H : 0) + h;

    float acc0 = 0.f, acc1 = 0.f;
    float wbuf[PF];
#pragma unroll
    for (int p = 0; p < PF; ++p) wbuf[p] = Wb[p * H];

    for (int kb = 0; kb < H - PF; kb += PF) {
#pragma unroll
        for (int p = 0; p < PF; ++p) {
            const float w = wbuf[p];
            wbuf[p] = Wb[(kb + p + PF) * H];
            acc0 = fmaf(e_s[r0][kb + p],     w, acc0);
            acc1 = fmaf(e_s[r0 + 1][kb + p], w, acc1);
        }
    }
#pragma unroll
    for (int p = 0; p < PF; ++p) {
        const int k = H - PF + p;
        acc0 = fmaf(e_s[r0][k],     wbuf[p], acc0);
        acc1 = fmaf(e_s[r0 + 1][k], wbuf[p], acc1);
    }

    if (q < 2) {                           // A = 0.5*(L~ + b1)
        const float bb = b1[h];
        float2 st; st.x = 0.5f * (acc0 + bb); st.y = 0.5f * (acc1 + bb);
        *reinterpret_cast<float2*>(reinterpret_cast<float*>(&stageA[h]) + r0) = st;
    } else {                               // B = 0.5*R~ ; c partials = w*R~
        const float w2h = W2[h];
        float2 st; st.x = 0.5f * acc0; st.y = 0.5f * acc1;
        *reinterpret_cast<float2*>(reinterpret_cast<float*>(&stageB[h]) + r0) = st;
        float s0 = w2h * acc0, s1 = w2h * acc1;
#pragma unroll
        for (int off = 32; off; off >>= 1) {
            s0 += __shfl_xor(s0, off);
            s1 += __shfl_xor(s1, off);
        }
        const int wv = t >> 6;             // 4..7
        if ((t & 63) == 0) { cred[wv - 4][0] = s0; cred[wv - 4][1] = s1; }
    }
    __syncthreads();

    if (t < 4)
        c[i0 + t] = cred[(t >> 1) * 2][t & 1] + cred[(t >> 1) * 2 + 1][t & 1];
    if (t < H)
        *reinterpret_cast<float4*>(&At[t * N + i0]) = stageA[t];
    else if (t >= 256 && t < 256 + H)
        *reinterpret_cast<float4*>(&Bt[(t - 256) * N + i0]) = stageB[t - 256];
}

// ---------------------------------------------------------------------------
// adj: grid N/4 = 256 blocks x 512 threads (2 waves/SIMD).
//   thread t: rows i0..i0+3, cols j0 = 2t, 2t+1.
//   ZERO in-loop LDS: A (float4, wave-uniform addr -> scalar/K$) and W2[s]
//   (uniform scalar) stay off the LDS pipe; B is a coalesced float2 stream.
//   Both A and B have 8-deep static rotating prefetch. Per h per thread:
//   16 VALU (v_add + v_fma with |.| modifier), 1 float2 VMEM, 2 uniform
//   loads. Block-local softmax over j.
// ---------------------------------------------------------------------------
__global__ __launch_bounds__(512) void adj_kernel(
    const float* __restrict__ At, const float* __restrict__ Bt,
    const float* __restrict__ W2, const float* __restrict__ c,
    float* __restrict__ out)
{
    constexpr int II = 4;
    __shared__ float red_m[II][8];
    __shared__ float red_s[II][8];

    const int t = threadIdx.x;
    const int lane = t & 63, wave = t >> 6;
    const int i0 = blockIdx.x * II;
    const int j0 = t * 2;

    const float2 cj = *reinterpret_cast<const float2*>(&c[j0]);
    float accx[II], accy[II];
#pragma unroll
    for (int ii = 0; ii < II; ++ii) { accx[ii] = 0.5f * cj.x; accy[ii] = 0.5f * cj.y; }

    const float* Bp = Bt + j0;
    float2 rbuf[8];
    float4 abuf[8];
#pragma unroll
    for (int p = 0; p < 8; ++p) {
        rbuf[p] = *reinterpret_cast<const float2*>(&Bp[p * N]);
        abuf[p] = *reinterpret_cast<const float4*>(&At[p * N + i0]);
    }

#pragma unroll 1
    for (int g = 0; g < H / 8; ++g) {
#pragma unroll
        for (int p = 0; p < 8; ++p) {
            const int s = 8 * g + p;
            const float2 r = rbuf[p];
            const float4 A = abuf[p];
            rbuf[p] = *reinterpret_cast<const float2*>(&Bp[(s + 8) * N]);
            abuf[p] = *reinterpret_cast<const float4*>(&At[(s + 8) * N + i0]);
            const float w = W2[s];         // SIGNED w2 — uniform -> s_load
            const float* Ap = &A.x;
#pragma unroll
            for (int ii = 0; ii < II; ++ii) {
                accx[ii] = fmaf(w, fabsf(Ap[ii] + r.x), accx[ii]);
                accy[ii] = fmaf(w, fabsf(Ap[ii] + r.y), accy[ii]);
            }
        }
    }

    // ---- softmax over j (block = full row) ----
#pragma unroll
    for (int ii = 0; ii < II; ++ii) {
        float m = fmaxf(accx[ii], accy[ii]);
#pragma unroll
        for (int off = 32; off; off >>= 1) m = fmaxf(m, __shfl_xor(m, off));
        if (lane == 0) red_m[ii][wave] = m;
    }
    __syncthreads();

    float mm[II];
#pragma unroll
    for (int ii = 0; ii < II; ++ii) {
        float m = red_m[ii][0];
#pragma unroll
        for (int w = 1; w < 8; ++w) m = fmaxf(m, red_m[ii][w]);
        mm[ii] = m;
    }

#pragma unroll
    for (int ii = 0; ii < II; ++ii) {
        accx[ii] = expf(accx[ii] - mm[ii]);
        accy[ii] = expf(accy[ii] - mm[ii]);
        float s = accx[ii] + accy[ii];
#pragma unroll
        for (int off = 32; off; off >>= 1) s += __shfl_xor(s, off);
        if (lane == 0) red_s[ii][wave] = s;
    }
    __syncthreads();

#pragma unroll
    for (int ii = 0; ii < II; ++ii) {
        float s = red_s[ii][0];
#pragma unroll
        for (int w = 1; w < 8; ++w) s += red_s[ii][w];
        const float rcp = 1.0f / s;
        float2 o;
        o.x = accx[ii] * rcp;
        o.y = accy[ii] * rcp;
        *reinterpret_cast<float2*>(&out[(i0 + ii) * N + j0]) = o;
    }
}

extern "C" void kernel_launch(void* const* d_in, const int* in_sizes, int n_in,
                              void* d_out, int out_size, void* d_ws, size_t ws_size,
                              hipStream_t stream) {
    const float* x  = (const float*)d_in[0];   // (N,H)
    const float* W1 = (const float*)d_in[1];   // (2H,H)
    const float* b1 = (const float*)d_in[2];   // (H,)
    const float* W2 = (const float*)d_in[3];   // (H,1)
    // d_in[4] = b2 — cancels under softmax, not needed.
    float* out = (float*)d_out;

    float* wsf = (float*)d_ws;
    float* At = wsf;                     // HPAD*N
    float* Bt = At + HPAD * N;           // HPAD*N
    float* cc = Bt + HPAD * N;           // N

    prep_kernel<<<N / 4, 512, 0, stream>>>(x, W1, b1, W2, At, Bt, cc);
    adj_kernel<<<N / 4, 512, 0, stream>>>(At, Bt, W2, cc, out);
}

// Round 9
// 29.143 us; speedup vs baseline: 1.1377x; 1.0410x over previous
//
#include <hip/hip_runtime.h>

#define H 128
#define N 1024
#define HPAD 144   // Bt rows: 128 + 16 prefetch over-read slack

// ---------------------------------------------------------------------------
// Identity: relu(v)*w = 0.5*w*v + w*|v/2|,  v = L~ + b1 + R~  (w SIGNED)
//   logit[i][j] = const_i + 0.5*c_j + sum_h w_h * |A[h,i] + B[h,j]|
//   A = 0.5*(L~+b1), B = 0.5*R~, c_j = sum_h w_h*R~[j,h]; const_i and b2
//   cancel in softmax.
//
// prep: grid N/4 = 256 blocks x 512 threads (round-8 version, verified).
// ---------------------------------------------------------------------------
__global__ __launch_bounds__(512) void prep_kernel(
    const float* __restrict__ x, const float* __restrict__ W1,
    const float* __restrict__ b1, const float* __restrict__ W2,
    float* __restrict__ At, float* __restrict__ Bt,
    float* __restrict__ c)
{
    constexpr int PF = 8;
    __shared__ float e_s[4][H];
    __shared__ float cred[4][2];
    __shared__ float4 stageA[H];
    __shared__ float4 stageB[H];
    const int t = threadIdx.x;
    const int i0 = blockIdx.x * 4;

    // ---- normalize rows (waves 0-3, wave w owns row w) ----
    if (t < 256) {
        const int row = t >> 6, lane = t & 63;
        const float2 v = *reinterpret_cast<const float2*>(&x[(i0 + row) * H + 2 * lane]);
        float s = v.x * v.x + v.y * v.y;
#pragma unroll
        for (int off = 32; off; off >>= 1) s += __shfl_xor(s, off);
        const float rn = 1.0f / fmaxf(sqrtf(s), 1e-12f);
        e_s[row][2 * lane]     = v.x * rn;
        e_s[row][2 * lane + 1] = v.y * rn;
    }
    __syncthreads();

    // ---- dual GEMV, PF=8 register-pipelined W1 column loads ----
    const int h = t & (H - 1);
    const int q = t >> 7;                  // 0,1 -> A ; 2,3 -> B
    const int r0 = (q & 1) * 2;            // row pair {0,1} or {2,3}
    const float* Wb = W1 + (q >= 2 ? H * H : 0) + h;

    float acc0 = 0.f, acc1 = 0.f;
    float wbuf[PF];
#pragma unroll
    for (int p = 0; p < PF; ++p) wbuf[p] = Wb[p * H];

    for (int kb = 0; kb < H - PF; kb += PF) {
#pragma unroll
        for (int p = 0; p < PF; ++p) {
            const float w = wbuf[p];
            wbuf[p] = Wb[(kb + p + PF) * H];
            acc0 = fmaf(e_s[r0][kb + p],     w, acc0);
            acc1 = fmaf(e_s[r0 + 1][kb + p], w, acc1);
        }
    }
#pragma unroll
    for (int p = 0; p < PF; ++p) {
        const int k = H - PF + p;
        acc0 = fmaf(e_s[r0][k],     wbuf[p], acc0);
        acc1 = fmaf(e_s[r0 + 1][k], wbuf[p], acc1);
    }

    if (q < 2) {                           // A = 0.5*(L~ + b1)
        const float bb = b1[h];
        float2 st; st.x = 0.5f * (acc0 + bb); st.y = 0.5f * (acc1 + bb);
        *reinterpret_cast<float2*>(reinterpret_cast<float*>(&stageA[h]) + r0) = st;
    } else {                               // B = 0.5*R~ ; c partials = w*R~
        const float w2h = W2[h];
        float2 st; st.x = 0.5f * acc0; st.y = 0.5f * acc1;
        *reinterpret_cast<float2*>(reinterpret_cast<float*>(&stageB[h]) + r0) = st;
        float s0 = w2h * acc0, s1 = w2h * acc1;
#pragma unroll
        for (int off = 32; off; off >>= 1) {
            s0 += __shfl_xor(s0, off);
            s1 += __shfl_xor(s1, off);
        }
        const int wv = t >> 6;             // 4..7
        if ((t & 63) == 0) { cred[wv - 4][0] = s0; cred[wv - 4][1] = s1; }
    }
    __syncthreads();

    if (t < 4)
        c[i0 + t] = cred[(t >> 1) * 2][t & 1] + cred[(t >> 1) * 2 + 1][t & 1];
    if (t < H)
        *reinterpret_cast<float4*>(&At[t * N + i0]) = stageA[t];
    else if (t >= 256 && t < 256 + H)
        *reinterpret_cast<float4*>(&Bt[(t - 256) * N + i0]) = stageB[t - 256];
}

// ---------------------------------------------------------------------------
// adj: R3 skeleton. grid N/4 = 256 blocks x 512 threads (2 waves/SIMD).
//   thread t: rows i0..i0+3, cols j0 = 2t, 2t+1.
//   Per h: 1 ds_read_b128 (A, LDS broadcast) + 1 coalesced float2 VMEM (B)
//   + 1 uniform scalar W2[s] (scalar pipe) + 16 VALU
//   (v_add + v_fma w/ |.| modifier; w in SGPR -> 1 SGPR operand, legal).
//   Deltas vs R3: no sgn LDS read; PF=16 rotating B prefetch (2-phase
//   body keeps slot indices static); W2 prefetched 1 group ahead.
// ---------------------------------------------------------------------------
__global__ __launch_bounds__(512) void adj_kernel(
    const float* __restrict__ At, const float* __restrict__ Bt,
    const float* __restrict__ W2, const float* __restrict__ c,
    float* __restrict__ out)
{
    constexpr int II = 4;
    __shared__ float4 LsT[H];
    __shared__ float red_m[II][8];
    __shared__ float red_s[II][8];

    const int t = threadIdx.x;
    const int lane = t & 63, wave = t >> 6;
    const int i0 = blockIdx.x * II;
    const int j0 = t * 2;

    if (t < H)
        LsT[t] = *reinterpret_cast<const float4*>(&At[t * N + i0]);
    const float2 cj = *reinterpret_cast<const float2*>(&c[j0]);
    __syncthreads();

    float accx[II], accy[II];
#pragma unroll
    for (int ii = 0; ii < II; ++ii) { accx[ii] = 0.5f * cj.x; accy[ii] = 0.5f * cj.y; }

    const float* Bp = Bt + j0;
    float2 rbuf[16];
#pragma unroll
    for (int p = 0; p < 16; ++p)
        rbuf[p] = *reinterpret_cast<const float2*>(&Bp[p * N]);
    float wA[8], wB[8];
#pragma unroll
    for (int p = 0; p < 8; ++p) { wA[p] = W2[p]; wB[p] = W2[8 + p]; }

#pragma unroll 1
    for (int gg = 0; gg < 8; ++gg) {
        // ---- half A: s = 16*gg + p, slots p ----
#pragma unroll
        for (int p = 0; p < 8; ++p) {
            const int s = 16 * gg + p;
            const float2 r = rbuf[p];
            rbuf[p] = *reinterpret_cast<const float2*>(&Bp[(s + 16) * N]);
            const float w = wA[p];
            wA[p] = W2[(s + 16) & 127];
            const float4 lv = LsT[s];
            const float* Ap = &lv.x;
#pragma unroll
            for (int ii = 0; ii < II; ++ii) {
                accx[ii] = fmaf(w, fabsf(Ap[ii] + r.x), accx[ii]);
                accy[ii] = fmaf(w, fabsf(Ap[ii] + r.y), accy[ii]);
            }
        }
        // ---- half B: s = 16*gg + 8 + p, slots 8+p ----
#pragma unroll
        for (int p = 0; p < 8; ++p) {
            const int s = 16 * gg + 8 + p;
            const float2 r = rbuf[8 + p];
            rbuf[8 + p] = *reinterpret_cast<const float2*>(&Bp[(s + 16) * N]);
            const float w = wB[p];
            wB[p] = W2[(s + 16) & 127];
            const float4 lv = LsT[s];
            const float* Ap = &lv.x;
#pragma unroll
            for (int ii = 0; ii < II; ++ii) {
                accx[ii] = fmaf(w, fabsf(Ap[ii] + r.x), accx[ii]);
                accy[ii] = fmaf(w, fabsf(Ap[ii] + r.y), accy[ii]);
            }
        }
    }

    // ---- softmax over j (block = full row) ----
#pragma unroll
    for (int ii = 0; ii < II; ++ii) {
        float m = fmaxf(accx[ii], accy[ii]);
#pragma unroll
        for (int off = 32; off; off >>= 1) m = fmaxf(m, __shfl_xor(m, off));
        if (lane == 0) red_m[ii][wave] = m;
    }
    __syncthreads();

    float mm[II];
#pragma unroll
    for (int ii = 0; ii < II; ++ii) {
        float m = red_m[ii][0];
#pragma unroll
        for (int w = 1; w < 8; ++w) m = fmaxf(m, red_m[ii][w]);
        mm[ii] = m;
    }

#pragma unroll
    for (int ii = 0; ii < II; ++ii) {
        accx[ii] = expf(accx[ii] - mm[ii]);
        accy[ii] = expf(accy[ii] - mm[ii]);
        float s = accx[ii] + accy[ii];
#pragma unroll
        for (int off = 32; off; off >>= 1) s += __shfl_xor(s, off);
        if (lane == 0) red_s[ii][wave] = s;
    }
    __syncthreads();

#pragma unroll
    for (int ii = 0; ii < II; ++ii) {
        float s = red_s[ii][0];
#pragma unroll
        for (int w = 1; w < 8; ++w) s += red_s[ii][w];
        const float rcp = 1.0f / s;
        float2 o;
        o.x = accx[ii] * rcp;
        o.y = accy[ii] * rcp;
        *reinterpret_cast<float2*>(&out[(i0 + ii) * N + j0]) = o;
    }
}

extern "C" void kernel_launch(void* const* d_in, const int* in_sizes, int n_in,
                              void* d_out, int out_size, void* d_ws, size_t ws_size,
                              hipStream_t stream) {
    const float* x  = (const float*)d_in[0];   // (N,H)
    const float* W1 = (const float*)d_in[1];   // (2H,H)
    const float* b1 = (const float*)d_in[2];   // (H,)
    const float* W2 = (const float*)d_in[3];   // (H,1)
    // d_in[4] = b2 — cancels under softmax, not needed.
    float* out = (float*)d_out;

    float* wsf = (float*)d_ws;
    float* At = wsf;                     // HPAD*N (only first H rows used)
    float* Bt = At + HPAD * N;           // HPAD*N (rows >= H only prefetched)
    float* cc = Bt + HPAD * N;           // N

    prep_kernel<<<N / 4, 512, 0, stream>>>(x, W1, b1, W2, At, Bt, cc);
    adj_kernel<<<N / 4, 512, 0, stream>>>(At, Bt, W2, cc, out);
}

// Round 10
// 27.710 us; speedup vs baseline: 1.1965x; 1.0517x over previous
//
#include <hip/hip_runtime.h>

#define H 128
#define N 1024

// ---------------------------------------------------------------------------
// EXACT round-3 winner (25.6 us) + ONE delta: the per-h sign coefficient
// comes from a 128-bit SGPR bitmask (SALU bit-test) instead of an LDS b32
// read. Identity (verified): with u = w2*(L+b1+R),
//   sum_h w2*relu(L+b1+R) = 0.5*const_i + 0.5*c_j + sum_h sign(w2_h)*0.5*|u|
// const_i and b2 cancel under softmax; c pre-halved in prep.
//
// prep: grid N/4 = 256 blocks x 512 threads.
//   waves 0-3 normalize rows; quarter q = t>>7: q<2 -> L-half, q>=2 -> R-half;
//   rows {0,1} (q even) or {2,3} (q odd); h = t&127; PF=8 register-pipelined
//   W1 column loads. Outputs (w2-scaled):
//     Lp[i][h] = w2[h]*(L[i][h]+b1[h])   (row-major, coalesced stores)
//     Rt[h][j] = w2[h]*R[j][h]           (transposed for adj)
//     c[j] = 0.5*sum_h Rt[h][j];  mask[0..1] = sign ballot of W2 (block 0)
// ---------------------------------------------------------------------------
__global__ __launch_bounds__(512) void prep_kernel(
    const float* __restrict__ x, const float* __restrict__ W1,
    const float* __restrict__ b1, const float* __restrict__ W2,
    float* __restrict__ Lp, float* __restrict__ Rt, float* __restrict__ c,
    unsigned long long* __restrict__ mask)
{
    constexpr int PF = 8;
    __shared__ float e_s[4][H];
    __shared__ float cred[4][2];
    const int t = threadIdx.x;
    const int i0 = blockIdx.x * 4;

    // ---- sign ballot (waves 0,1 cover h = t), block 0 publishes ----
    if (t < 128) {
        const bool pos = (W2[t] >= 0.f);
        const unsigned long long bal = __ballot(pos);
        if (blockIdx.x == 0 && (t & 63) == 0) mask[t >> 6] = bal;
    }
    // ---- normalize rows (waves 0-3, wave w owns row w) ----
    if (t < 256) {
        const int row = t >> 6, lane = t & 63;
        const float2 v = *reinterpret_cast<const float2*>(&x[(i0 + row) * H + 2 * lane]);
        float s = v.x * v.x + v.y * v.y;
#pragma unroll
        for (int off = 32; off; off >>= 1) s += __shfl_xor(s, off);
        const float rn = 1.0f / fmaxf(sqrtf(s), 1e-12f);
        e_s[row][2 * lane]     = v.x * rn;
        e_s[row][2 * lane + 1] = v.y * rn;
    }
    __syncthreads();

    const int h = t & (H - 1);
    const int q = t >> 7;                // 0,1 -> L ; 2,3 -> R
    const int r0 = (q & 1) * 2;          // row pair {0,1} or {2,3}
    const float* Wb = W1 + (q >= 2 ? H * H : 0) + h;

    float acc0 = 0.f, acc1 = 0.f;
    float wbuf[PF];
#pragma unroll
    for (int p = 0; p < PF; ++p) wbuf[p] = Wb[p * H];

    for (int kb = 0; kb < H - PF; kb += PF) {
#pragma unroll
        for (int p = 0; p < PF; ++p) {
            const float w = wbuf[p];
            wbuf[p] = Wb[(kb + p + PF) * H];
            acc0 = fmaf(e_s[r0][kb + p],     w, acc0);
            acc1 = fmaf(e_s[r0 + 1][kb + p], w, acc1);
        }
    }
#pragma unroll
    for (int p = 0; p < PF; ++p) {
        const int k = H - PF + p;
        acc0 = fmaf(e_s[r0][k],     wbuf[p], acc0);
        acc1 = fmaf(e_s[r0 + 1][k], wbuf[p], acc1);
    }

    const float w2h = W2[h];
    if (q < 2) {
        const float bb = b1[h];
        Lp[(i0 + r0) * H + h]     = w2h * (acc0 + bb);
        Lp[(i0 + r0 + 1) * H + h] = w2h * (acc1 + bb);
    } else {
        const float v0 = w2h * acc0, v1 = w2h * acc1;
        Rt[h * N + (i0 + r0)]     = v0;
        Rt[h * N + (i0 + r0 + 1)] = v1;
        float s0 = v0, s1 = v1;          // c_j partial sums over h
#pragma unroll
        for (int off = 32; off; off >>= 1) {
            s0 += __shfl_xor(s0, off);
            s1 += __shfl_xor(s1, off);
        }
        const int wv = t >> 6;           // 4..7
        if ((t & 63) == 0) { cred[wv - 4][0] = s0; cred[wv - 4][1] = s1; }
    }
    __syncthreads();
    if (t < 4) {
        const int r = t;
        c[i0 + r] = 0.5f * (cred[(r >> 1) * 2][r & 1] + cred[(r >> 1) * 2 + 1][r & 1]);
    }
}

// ---------------------------------------------------------------------------
// adj: grid N/4 = 256 blocks x 512 threads (8 waves -> 2 waves/SIMD).
//   thread t: rows i0..i0+3, cols j0 = 2t, 2t+1.
//   Per h: 1 ds_read_b128 (LsT broadcast) + 1 coalesced float2 VMEM (Rt,
//   PF=8 rotating prefetch) + SALU bit-test for w = sign(w2)*0.5 (SGPR
//   bitmask -- the single delta vs the 25.6 us kernel) + 16 VALU.
//   Block-local softmax over j.
// ---------------------------------------------------------------------------
__global__ __launch_bounds__(512) void adj_kernel(
    const float* __restrict__ Lp, const float* __restrict__ Rt,
    const unsigned long long* __restrict__ mask, const float* __restrict__ c,
    float* __restrict__ out)
{
    constexpr int II = 4, PF = 8;
    __shared__ float LsT[H][4];
    __shared__ float red_m[II][8];
    __shared__ float red_s[II][8];

    const int t = threadIdx.x;
    const int lane = t & 63, wave = t >> 6;
    const int i0 = blockIdx.x * II;
    const int j0 = t * 2;

    if (t < H) {
        float4 lv;
        lv.x = Lp[(i0 + 0) * H + t];
        lv.y = Lp[(i0 + 1) * H + t];
        lv.z = Lp[(i0 + 2) * H + t];
        lv.w = Lp[(i0 + 3) * H + t];
        *reinterpret_cast<float4*>(&LsT[t][0]) = lv;
    }
    const unsigned long long m0 = mask[0];   // uniform -> SGPR pair
    const unsigned long long m1 = mask[1];
    const float2 cj = *reinterpret_cast<const float2*>(&c[j0]);
    __syncthreads();

    float accx[II], accy[II];
#pragma unroll
    for (int ii = 0; ii < II; ++ii) { accx[ii] = cj.x; accy[ii] = cj.y; }

    float2 rbuf[PF];
#pragma unroll
    for (int p = 0; p < PF; ++p)
        rbuf[p] = *reinterpret_cast<const float2*>(&Rt[p * N + j0]);

    for (int hb = 0; hb < H - PF; hb += PF) {
#pragma unroll
        for (int p = 0; p < PF; ++p) {
            const int h = hb + p;
            const float2 r = rbuf[p];
            rbuf[p] = *reinterpret_cast<const float2*>(&Rt[(h + PF) * N + j0]);
            const float4 lv = *reinterpret_cast<const float4*>(&LsT[h][0]);
            const unsigned long long mm_ = (h < 64) ? m0 : m1;   // SALU
            const float s = ((mm_ >> (h & 63)) & 1ull) ? 0.5f : -0.5f;
            const float* lp = &lv.x;
#pragma unroll
            for (int ii = 0; ii < II; ++ii) {
                accx[ii] = fmaf(s, fabsf(lp[ii] + r.x), accx[ii]);
                accy[ii] = fmaf(s, fabsf(lp[ii] + r.y), accy[ii]);
            }
        }
    }
#pragma unroll
    for (int p = 0; p < PF; ++p) {       // tail, no prefetch
        const int h = H - PF + p;
        const float2 r = rbuf[p];
        const float4 lv = *reinterpret_cast<const float4*>(&LsT[h][0]);
        const float s = ((m1 >> (h & 63)) & 1ull) ? 0.5f : -0.5f;  // h>=120
        const float* lp = &lv.x;
#pragma unroll
        for (int ii = 0; ii < II; ++ii) {
            accx[ii] = fmaf(s, fabsf(lp[ii] + r.x), accx[ii]);
            accy[ii] = fmaf(s, fabsf(lp[ii] + r.y), accy[ii]);
        }
    }

    // ---- softmax over j (block = full row) ----
#pragma unroll
    for (int ii = 0; ii < II; ++ii) {
        float m = fmaxf(accx[ii], accy[ii]);
#pragma unroll
        for (int off = 32; off; off >>= 1) m = fmaxf(m, __shfl_xor(m, off));
        if (lane == 0) red_m[ii][wave] = m;
    }
    __syncthreads();

    float mm[II];
#pragma unroll
    for (int ii = 0; ii < II; ++ii) {
        float m = red_m[ii][0];
#pragma unroll
        for (int w = 1; w < 8; ++w) m = fmaxf(m, red_m[ii][w]);
        mm[ii] = m;
    }

#pragma unroll
    for (int ii = 0; ii < II; ++ii) {
        accx[ii] = expf(accx[ii] - mm[ii]);
        accy[ii] = expf(accy[ii] - mm[ii]);
        float s = accx[ii] + accy[ii];
#pragma unroll
        for (int off = 32; off; off >>= 1) s += __shfl_xor(s, off);
        if (lane == 0) red_s[ii][wave] = s;
    }
    __syncthreads();

#pragma unroll
    for (int ii = 0; ii < II; ++ii) {
        float s = red_s[ii][0];
#pragma unroll
        for (int w = 1; w < 8; ++w) s += red_s[ii][w];
        const float r = 1.0f / s;
        float2 o;
        o.x = accx[ii] * r;
        o.y = accy[ii] * r;
        *reinterpret_cast<float2*>(&out[(i0 + ii) * N + j0]) = o;
    }
}

extern "C" void kernel_launch(void* const* d_in, const int* in_sizes, int n_in,
                              void* d_out, int out_size, void* d_ws, size_t ws_size,
                              hipStream_t stream) {
    const float* x  = (const float*)d_in[0];   // (N,H)
    const float* W1 = (const float*)d_in[1];   // (2H,H)
    const float* b1 = (const float*)d_in[2];   // (H,)
    const float* W2 = (const float*)d_in[3];   // (H,1)
    // d_in[4] = b2 — cancels under softmax, not needed.
    float* out = (float*)d_out;

    float* Lp = (float*)d_ws;            // N*H
    float* Rt = Lp + N * H;              // H*N (w2-scaled, transposed)
    float* cc = Rt + H * N;              // N  (pre-halved; also absorbs
                                         //     the 8-row prefetch over-read)
    unsigned long long* mask = (unsigned long long*)(cc + N + 16 * N);

    prep_kernel<<<N / 4, 512, 0, stream>>>(x, W1, b1, W2, Lp, Rt, cc, mask);
    adj_kernel<<<N / 4, 512, 0, stream>>>(Lp, Rt, mask, cc, out);
}

// Round 11
// 25.496 us; speedup vs baseline: 1.3004x; 1.0868x over previous
//
#include <hip/hip_runtime.h>

#define H 128
#define N 1024

// ---------------------------------------------------------------------------
// prep: grid N/4 = 256 blocks x 512 threads (8 waves -> 8 waves/CU).
//   phase 1: waves 0-3 L2-normalize rows 0-3 (shuffle reduce).
//   phase 2: quarter q = t>>7: q<2 -> L-half of W1, q>=2 -> R-half;
//            rows {0,1} (q even) or {2,3} (q odd); h = t&127.
//            PF=8 register-pipelined W1 column loads.
//   Outputs (all scaled by w2[h], so relu(x)*w2 = s*|u| works downstream):
//     Lp[i][h] = w2[h]*(L[i][h] + b1[h])
//     Rt[h][j] = w2[h]*R[j][h]          (transposed for adj)
//     c[j]     = 0.5 * sum_h Rt[h][j]   (softmax-invariant part of logits)
// ---------------------------------------------------------------------------
__global__ __launch_bounds__(512) void prep_kernel(
    const float* __restrict__ x, const float* __restrict__ W1,
    const float* __restrict__ b1, const float* __restrict__ W2,
    float* __restrict__ Lp, float* __restrict__ Rt, float* __restrict__ c)
{
    constexpr int PF = 8;
    __shared__ float e_s[4][H];
    __shared__ float cred[4][2];
    const int t = threadIdx.x;
    const int i0 = blockIdx.x * 4;

    if (t < 256) {                       // normalize: wave w owns row w
        const int row = t >> 6, lane = t & 63;
        const float2 v = *reinterpret_cast<const float2*>(&x[(i0 + row) * H + 2 * lane]);
        float s = v.x * v.x + v.y * v.y;
#pragma unroll
        for (int off = 32; off; off >>= 1) s += __shfl_xor(s, off);
        const float rn = 1.0f / fmaxf(sqrtf(s), 1e-12f);
        e_s[row][2 * lane]     = v.x * rn;
        e_s[row][2 * lane + 1] = v.y * rn;
    }
    __syncthreads();

    const int h = t & (H - 1);
    const int q = t >> 7;                // 0,1 -> L ; 2,3 -> R
    const int r0 = (q & 1) * 2;          // row pair {0,1} or {2,3}
    const float* Wb = W1 + (q >= 2 ? H * H : 0) + h;

    float acc0 = 0.f, acc1 = 0.f;
    float wbuf[PF];
#pragma unroll
    for (int p = 0; p < PF; ++p) wbuf[p] = Wb[p * H];

    for (int kb = 0; kb < H - PF; kb += PF) {
#pragma unroll
        for (int p = 0; p < PF; ++p) {
            const float w = wbuf[p];
            wbuf[p] = Wb[(kb + p + PF) * H];
            acc0 = fmaf(e_s[r0][kb + p],     w, acc0);
            acc1 = fmaf(e_s[r0 + 1][kb + p], w, acc1);
        }
    }
#pragma unroll
    for (int p = 0; p < PF; ++p) {
        const int k = H - PF + p;
        acc0 = fmaf(e_s[r0][k],     wbuf[p], acc0);
        acc1 = fmaf(e_s[r0 + 1][k], wbuf[p], acc1);
    }

    const float w2h = W2[h];
    if (q < 2) {
        const float bb = b1[h];
        Lp[(i0 + r0) * H + h]     = w2h * (acc0 + bb);
        Lp[(i0 + r0 + 1) * H + h] = w2h * (acc1 + bb);
    } else {
        const float v0 = w2h * acc0, v1 = w2h * acc1;
        Rt[h * N + (i0 + r0)]     = v0;
        Rt[h * N + (i0 + r0 + 1)] = v1;
        float s0 = v0, s1 = v1;          // c_j partial sums over h
#pragma unroll
        for (int off = 32; off; off >>= 1) {
            s0 += __shfl_xor(s0, off);
            s1 += __shfl_xor(s1, off);
        }
        const int wv = t >> 6;           // 4..7
        if ((t & 63) == 0) { cred[wv - 4][0] = s0; cred[wv - 4][1] = s1; }
    }
    __syncthreads();
    if (t < 4) {                         // c[i0+r]: combine the 2 waves per row
        const int r = t;
        c[i0 + r] = 0.5f * (cred[(r >> 1) * 2][r & 1] + cred[(r >> 1) * 2 + 1][r & 1]);
    }
}

// ---------------------------------------------------------------------------
// adj: grid N/4 = 256 blocks x 512 threads (8 waves -> 2 waves/SIMD).
//   thread t: rows i0..i0+3, cols j0 = 2t, 2t+1.
//   logit'[i][j] = c[j] + sum_h s_h * |Lp[i][h] + Rt[h][j]|,  s_h = ±0.5
//   (exactly sum_h relu(L+R+b1)*w2 minus a row constant -> same softmax).
//   Inner loop: 2 VALU/element (v_add + v_fma with abs modifier),
//   PF=8 float2 R-loads in flight, Lp via one b128 LDS broadcast per h.
// ---------------------------------------------------------------------------
__global__ __launch_bounds__(512) void adj_kernel(
    const float* __restrict__ Lp, const float* __restrict__ Rt,
    const float* __restrict__ W2, const float* __restrict__ c,
    float* __restrict__ out)
{
    constexpr int II = 4, PF = 8;
    __shared__ float LsT[H][4];
    __shared__ float sgn[H];
    __shared__ float red_m[II][8];
    __shared__ float red_s[II][8];

    const int t = threadIdx.x;
    const int lane = t & 63, wave = t >> 6;
    const int i0 = blockIdx.x * II;
    const int j0 = t * 2;

    if (t < H) {
        sgn[t] = (W2[t] >= 0.f) ? 0.5f : -0.5f;
        float4 lv;
        lv.x = Lp[(i0 + 0) * H + t];
        lv.y = Lp[(i0 + 1) * H + t];
        lv.z = Lp[(i0 + 2) * H + t];
        lv.w = Lp[(i0 + 3) * H + t];
        *reinterpret_cast<float4*>(&LsT[t][0]) = lv;
    }
    const float2 cj = *reinterpret_cast<const float2*>(&c[j0]);
    __syncthreads();

    float accx[II], accy[II];
#pragma unroll
    for (int ii = 0; ii < II; ++ii) { accx[ii] = cj.x; accy[ii] = cj.y; }

    float2 rbuf[PF];
#pragma unroll
    for (int p = 0; p < PF; ++p)
        rbuf[p] = *reinterpret_cast<const float2*>(&Rt[p * N + j0]);

    for (int hb = 0; hb < H - PF; hb += PF) {
#pragma unroll
        for (int p = 0; p < PF; ++p) {
            const int h = hb + p;
            const float2 r = rbuf[p];
            rbuf[p] = *reinterpret_cast<const float2*>(&Rt[(h + PF) * N + j0]);
            const float4 lv = *reinterpret_cast<const float4*>(&LsT[h][0]);
            const float s = sgn[h];
            const float* lp = &lv.x;
#pragma unroll
            for (int ii = 0; ii < II; ++ii) {
                accx[ii] = fmaf(s, fabsf(lp[ii] + r.x), accx[ii]);
                accy[ii] = fmaf(s, fabsf(lp[ii] + r.y), accy[ii]);
            }
        }
    }
#pragma unroll
    for (int p = 0; p < PF; ++p) {       // tail, no prefetch
        const int h = H - PF + p;
        const float2 r = rbuf[p];
        const float4 lv = *reinterpret_cast<const float4*>(&LsT[h][0]);
        const float s = sgn[h];
        const float* lp = &lv.x;
#pragma unroll
        for (int ii = 0; ii < II; ++ii) {
            accx[ii] = fmaf(s, fabsf(lp[ii] + r.x), accx[ii]);
            accy[ii] = fmaf(s, fabsf(lp[ii] + r.y), accy[ii]);
        }
    }

    // ---- softmax over j (block = full row) ----
#pragma unroll
    for (int ii = 0; ii < II; ++ii) {
        float m = fmaxf(accx[ii], accy[ii]);
#pragma unroll
        for (int off = 32; off; off >>= 1) m = fmaxf(m, __shfl_xor(m, off));
        if (lane == 0) red_m[ii][wave] = m;
    }
    __syncthreads();

    float mm[II];
#pragma unroll
    for (int ii = 0; ii < II; ++ii) {
        float m = red_m[ii][0];
#pragma unroll
        for (int w = 1; w < 8; ++w) m = fmaxf(m, red_m[ii][w]);
        mm[ii] = m;
    }

#pragma unroll
    for (int ii = 0; ii < II; ++ii) {
        accx[ii] = expf(accx[ii] - mm[ii]);
        accy[ii] = expf(accy[ii] - mm[ii]);
        float s = accx[ii] + accy[ii];
#pragma unroll
        for (int off = 32; off; off >>= 1) s += __shfl_xor(s, off);
        if (lane == 0) red_s[ii][wave] = s;
    }
    __syncthreads();

#pragma unroll
    for (int ii = 0; ii < II; ++ii) {
        float s = red_s[ii][0];
#pragma unroll
        for (int w = 1; w < 8; ++w) s += red_s[ii][w];
        const float r = 1.0f / s;
        float2 o;
        o.x = accx[ii] * r;
        o.y = accy[ii] * r;
        *reinterpret_cast<float2*>(&out[(i0 + ii) * N + j0]) = o;
    }
}

extern "C" void kernel_launch(void* const* d_in, const int* in_sizes, int n_in,
                              void* d_out, int out_size, void* d_ws, size_t ws_size,
                              hipStream_t stream) {
    const float* x  = (const float*)d_in[0];   // (N,H)
    const float* W1 = (const float*)d_in[1];   // (2H,H)
    const float* b1 = (const float*)d_in[2];   // (H,)
    const float* W2 = (const float*)d_in[3];   // (H,1)
    // d_in[4] = b2 — cancels under softmax, not needed.
    float* out = (float*)d_out;

    float* Lp = (float*)d_ws;        // N*H
    float* Rt = Lp + N * H;          // H*N (transposed, w2-scaled)
    float* cc = Rt + H * N;          // N

    prep_kernel<<<N / 4, 512, 0, stream>>>(x, W1, b1, W2, Lp, Rt, cc);
    adj_kernel<<<N / 4, 512, 0, stream>>>(Lp, Rt, W2, cc, out);
}